// Round 15
// baseline (287.054 us; speedup 1.0000x reference)
//
#include <hip/hip_runtime.h>

constexpr int NN    = 128;
constexpr int BB    = 2;
constexpr int DIN   = 128;
constexpr int DD    = 256;
constexpr int DFF   = 1024;
constexpr int NH    = 8;
constexpr int DH    = 32;
constexpr int NL    = 2;
constexpr int BLK   = 32;
constexpr int WMAX  = 2 * BLK + 1;       // 65
constexpr int RROWS = NN * WMAX * BB;    // 16640

typedef __attribute__((ext_vector_type(8))) short s16x8;   // 8 bf16 (4 VGPR)
typedef __attribute__((ext_vector_type(4))) float f32x4;

__device__ __forceinline__ ushort f2bf(float f) {
  unsigned u = __float_as_uint(f);
  unsigned r = (u + 0x7fffu + ((u >> 16) & 1u)) >> 16;    // RNE
  return (ushort)r;
}
__device__ __forceinline__ float bf2f(ushort h) {
  return __uint_as_float(((unsigned)h) << 16);
}

// async global->LDS, 16B per lane; LDS dest must be lane-linear.
__device__ __forceinline__ void gld16(const void* g, void* l) {
  __builtin_amdgcn_global_load_lds(
      (const __attribute__((address_space(1))) void*)g,
      (__attribute__((address_space(3))) void*)l, 16, 0, 0);
}
// vmcnt(0) BEFORE any barrier that publishes global_load_lds data.
__device__ __forceinline__ void vmdrain() {
  asm volatile("s_waitcnt vmcnt(0)" ::: "memory");
}

// ---------------------------------------------------------------------------
// Fused prep: [0,256) kp rows, [256,2176) weight transpose tiles.
// ---------------------------------------------------------------------------
struct TD { const float* in; ushort* out; int K; int N; };
struct TPack { TD d[10]; };
constexpr int KP_BLOCKS   = NN * BB;             // 256
constexpr int WCONV_TILES = 1920;

__global__ __launch_bounds__(256) void k_prep(
    TPack p, const float* __restrict__ inp,
    const float* __restrict__ kW1, const float* __restrict__ kb1,
    const float* __restrict__ kW2, const float* __restrict__ kb2,
    float* __restrict__ kp) {
  __shared__ float ls[32 * 33];
  int bid = blockIdx.x;
  int tid = threadIdx.x;
  if (bid < KP_BLOCKS) {
    int row = bid;
    float* xs = ls;                 // [128]
    float* red = ls + 256;          // [8]
    if (tid < DIN) xs[tid] = inp[row * DIN + tid];
    __syncthreads();
    int j0 = tid * 4;
    float4 acc = *(const float4*)(kb1 + j0);
#pragma unroll 8
    for (int k = 0; k < DIN; ++k) {
      float xv = xs[k];
      float4 wv = *(const float4*)(kW1 + (size_t)k * DFF + j0);
      acc.x += xv * wv.x; acc.y += xv * wv.y;
      acc.z += xv * wv.z; acc.w += xv * wv.w;
    }
    acc.x = fmaxf(acc.x, 0.f); acc.y = fmaxf(acc.y, 0.f);
    acc.z = fmaxf(acc.z, 0.f); acc.w = fmaxf(acc.w, 0.f);
    float4 w2a = *(const float4*)(kW2 + 2 * j0);
    float4 w2b = *(const float4*)(kW2 + 2 * j0 + 4);
    float a0 = acc.x * w2a.x + acc.y * w2a.z + acc.z * w2b.x + acc.w * w2b.z;
    float a1 = acc.x * w2a.y + acc.y * w2a.w + acc.z * w2b.y + acc.w * w2b.w;
#pragma unroll
    for (int m = 32; m > 0; m >>= 1) {
      a0 += __shfl_xor(a0, m, 64);
      a1 += __shfl_xor(a1, m, 64);
    }
    if ((tid & 63) == 0) { red[(tid >> 6) * 2] = a0; red[(tid >> 6) * 2 + 1] = a1; }
    __syncthreads();
    if (tid == 0) {
      kp[row * 2 + 0] = red[0] + red[2] + red[4] + red[6] + kb2[0];
      kp[row * 2 + 1] = red[1] + red[3] + red[5] + red[7] + kb2[1];
    }
  } else {
    const int cum[11] = {0, 128, 384, 576, 768, 832, 896, 1152, 1408, 1664, 1920};
    int tb = bid - KP_BLOCKS;
    int mi = 0;
#pragma unroll
    for (int i = 0; i < 10; ++i) if (tb >= cum[i + 1]) mi = i + 1;
    TD t = p.d[mi];
    int tile = tb - cum[mi];
    int ntk = t.K >> 5;
    int tn = tile / ntk, tk = tile - tn * ntk;
    int r = tid >> 5, c = tid & 31;
#pragma unroll
    for (int i = 0; i < 4; ++i) {
      int kk = r + 8 * i;
      ls[kk * 33 + c] = t.in[(size_t)(tk * 32 + kk) * t.N + tn * 32 + c];
    }
    __syncthreads();
#pragma unroll
    for (int i = 0; i < 4; ++i) {
      int rr = r + 8 * i;
      t.out[(size_t)(tn * 32 + rr) * t.K + tk * 32 + c] = f2bf(ls[c * 33 + rr]);
    }
  }
}

// ---------------------------------------------------------------------------
// inMLP1: t = relu(x @ inW1^T + b1), x = inputs + PE computed on the fly.
// ---------------------------------------------------------------------------
__global__ __launch_bounds__(512) void k_inmlp1(
    const float* __restrict__ inp, const ushort* __restrict__ Bt,
    const float* __restrict__ bias, ushort* __restrict__ out) {
  __shared__ __align__(16) char As[128 * 128];   // 16 KB
  __shared__ __align__(16) char Bs[256 * 128];   // 32 KB
  int tid = threadIdx.x;
  int m0 = blockIdx.x * 128, n0 = blockIdx.y * 256;
  int lane = tid & 63, w = tid >> 6;
  int wr = w >> 2, wc = w & 3;
  int fr = lane & 15, g = lane >> 4;
  f32x4 acc[4][4] = {};

  for (int kb = 0; kb < DIN; kb += 64) {
    for (int e = tid; e < 256 * 8; e += 512) {
      int row = e >> 3, c = e & 7;
      gld16(Bt + (size_t)(n0 + row) * DIN + kb + ((c ^ (row & 7)) * 8), Bs + e * 16);
    }
    for (int e = tid; e < 128 * 8; e += 512) {
      int row = e >> 3, c = e & 7;
      int r = m0 + row;
      int n = r / (WMAX * BB);
      int rem = r - n * (WMAX * BB);
      int wn = rem >> 1, b = rem & 1;
      int st = n - BLK; if (st < 0) st = 0;
      float pos = (float)(st + wn);
      const float* ip = inp + (n * BB + b) * DIN + kb + c * 8;
      ushort vals[8];
#pragma unroll
      for (int u = 0; u < 8; ++u) {
        int i = kb + c * 8 + u;
        float div = __expf(-0.0719557841f * (float)(i & 126));
        float ang = pos * div;
        float pe = (i & 1) ? __cosf(ang) : __sinf(ang);
        vals[u] = f2bf(ip[u] + pe);
      }
      *(uint4*)(As + ((row * 128 + c * 16) ^ ((row & 7) << 4))) = *(const uint4*)vals;
    }
    vmdrain();
    __syncthreads();
#pragma unroll
    for (int ks = 0; ks < 2; ++ks) {
      int kByte = ks * 64 + g * 16;
      s16x8 a[4], b[4];
#pragma unroll
      for (int m = 0; m < 4; ++m) {
        int row = wr * 64 + m * 16 + fr;
        a[m] = *(const s16x8*)(As + ((row * 128 + kByte) ^ ((row & 7) << 4)));
      }
#pragma unroll
      for (int n = 0; n < 4; ++n) {
        int row = wc * 64 + n * 16 + fr;
        b[n] = *(const s16x8*)(Bs + ((row * 128 + kByte) ^ ((row & 7) << 4)));
      }
#pragma unroll
      for (int m = 0; m < 4; ++m)
#pragma unroll
        for (int n = 0; n < 4; ++n)
          acc[m][n] = __builtin_amdgcn_mfma_f32_16x16x32_bf16(a[m], b[n], acc[m][n], 0, 0, 0);
    }
    __syncthreads();
  }
#pragma unroll
  for (int m = 0; m < 4; ++m) {
    int rowb = m0 + wr * 64 + m * 16 + g * 4;
#pragma unroll
    for (int n = 0; n < 4; ++n) {
      int col = n0 + wc * 64 + n * 16 + fr;
      float bv = bias[col];
#pragma unroll
      for (int j = 0; j < 4; ++j)
        out[(size_t)(rowb + j) * DFF + col] = f2bf(fmaxf(acc[m][n][j] + bv, 0.f));
    }
  }
}

// ---------------------------------------------------------------------------
// 8-wave MFMA GEMM, BN=256, gld16 staging (pre-swizzled source), single
// buffer, BK template. K-heavy kernels use BMT=32 + BK=128: 520 blocks ->
// 2 blocks/CU (72 KB LDS) AND 8 K-steps -- TLP hides the per-step drain.
// ---------------------------------------------------------------------------
template<int BMT, int RELU, int FUSE_LN, int BK>
__global__ __launch_bounds__(512) void k_gemm8(
    const ushort* __restrict__ A, const ushort* __restrict__ Bt,
    const float* __restrict__ bias, const ushort* __restrict__ resid,
    const float* __restrict__ lng, const float* __restrict__ lnb,
    ushort* __restrict__ out, int N, int K) {
  constexpr int MF   = (BMT + 31) / 32;
  constexpr int CPR  = BK / 8;
  constexpr int ROWB = BK * 2;
  __shared__ __align__(16) char As[BMT * ROWB];
  __shared__ __align__(16) char Bs[256 * ROWB];
  int tid = threadIdx.x;
  int m0 = blockIdx.x * BMT, n0 = blockIdx.y * 256;
  int lane = tid & 63, w = tid >> 6;
  int wr = w >> 2, wc = w & 3;
  int fr = lane & 15, g = lane >> 4;
  f32x4 acc[MF][4] = {};

  for (int kb = 0; kb < K; kb += BK) {
    for (int e = tid; e < BMT * CPR; e += 512) {
      int row = e / CPR, c = e % CPR;
      gld16(A + (size_t)(m0 + row) * K + kb + ((c ^ (row & 7)) * 8), As + e * 16);
    }
    for (int e = tid; e < 256 * CPR; e += 512) {
      int row = e / CPR, c = e % CPR;
      gld16(Bt + (size_t)(n0 + row) * K + kb + ((c ^ (row & 7)) * 8), Bs + e * 16);
    }
    vmdrain();
    __syncthreads();
#pragma unroll
    for (int ks = 0; ks < BK / 32; ++ks) {
      int kByte = ks * 64 + g * 16;
      s16x8 a[MF], b[4];
#pragma unroll
      for (int m = 0; m < MF; ++m) {
        int row = wr * (BMT / 2) + m * 16 + fr;
        a[m] = *(const s16x8*)(As + ((row * ROWB + kByte) ^ ((row & 7) << 4)));
      }
#pragma unroll
      for (int n = 0; n < 4; ++n) {
        int row = wc * 64 + n * 16 + fr;
        b[n] = *(const s16x8*)(Bs + ((row * ROWB + kByte) ^ ((row & 7) << 4)));
      }
#pragma unroll
      for (int m = 0; m < MF; ++m)
#pragma unroll
        for (int n = 0; n < 4; ++n)
          acc[m][n] = __builtin_amdgcn_mfma_f32_16x16x32_bf16(a[m], b[n], acc[m][n], 0, 0, 0);
    }
    __syncthreads();
  }

  if constexpr (!FUSE_LN) {
#pragma unroll
    for (int m = 0; m < MF; ++m) {
      int rowb = m0 + wr * (BMT / 2) + m * 16 + g * 4;
#pragma unroll
      for (int n = 0; n < 4; ++n) {
        int col = n0 + wc * 64 + n * 16 + fr;
        float bv = bias[col];
#pragma unroll
        for (int j = 0; j < 4; ++j) {
          float v = acc[m][n][j] + bv;
          if (RELU) v = fmaxf(v, 0.f);
          out[(size_t)(rowb + j) * N + col] = f2bf(v);
        }
      }
    }
  } else {
    float* psum = (float*)As;                 // [4][BMT]
    float* psq  = (float*)(As + 4 * BMT * 4); // [4][BMT]
#pragma unroll
    for (int m = 0; m < MF; ++m) {
      int rowb = wr * (BMT / 2) + m * 16 + g * 4;
#pragma unroll
      for (int j = 0; j < 4; ++j) {
        float ps = 0.f, pq = 0.f;
#pragma unroll
        for (int n = 0; n < 4; ++n) {
          int col = wc * 64 + n * 16 + fr;
          float v = acc[m][n][j] + bias[col]
                  + bf2f(resid[(size_t)(m0 + rowb + j) * 256 + col]);
          acc[m][n][j] = v;
          ps += v; pq += v * v;
        }
#pragma unroll
        for (int d = 1; d < 16; d <<= 1) {
          ps += __shfl_xor(ps, d, 64);
          pq += __shfl_xor(pq, d, 64);
        }
        if (fr == 0) { psum[wc * BMT + rowb + j] = ps; psq[wc * BMT + rowb + j] = pq; }
      }
    }
    __syncthreads();
#pragma unroll
    for (int m = 0; m < MF; ++m) {
      int rowb = wr * (BMT / 2) + m * 16 + g * 4;
#pragma unroll
      for (int j = 0; j < 4; ++j) {
        int lr = rowb + j;
        float sm = psum[lr] + psum[BMT + lr] + psum[2 * BMT + lr] + psum[3 * BMT + lr];
        float sq = psq[lr] + psq[BMT + lr] + psq[2 * BMT + lr] + psq[3 * BMT + lr];
        float mean = sm * (1.f / 256.f);
        float var = sq * (1.f / 256.f) - mean * mean;
        float rs = rsqrtf(var + 1e-5f);
#pragma unroll
        for (int n = 0; n < 4; ++n) {
          int col = wc * 64 + n * 16 + fr;
          float v = (acc[m][n][j] - mean) * rs * lng[col] + lnb[col];
          out[(size_t)(m0 + lr) * 256 + col] = f2bf(v);
        }
      }
    }
  }
}

// ---------------------------------------------------------------------------
// MFMA windowed attention. One block per (n,b,head), 5 waves.
// ---------------------------------------------------------------------------
constexpr int QKS = 40;
constexpr int VTS = 104;
constexpr int PS  = 104;

__device__ __forceinline__ int vslot(int d, int r) {
  int rc = r >> 3;
  int sw = (rc < 8) ? (rc ^ (d >> 3)) : rc;
  return d * VTS + sw * 8 + (r & 7);
}

__global__ __launch_bounds__(320) void k_attn(
    const ushort* __restrict__ qkv, ushort* __restrict__ o,
    const int* __restrict__ lenp) {
  __shared__ __align__(16) ushort Ks[80 * QKS];
  __shared__ __align__(16) ushort Vt[32 * VTS];
  __shared__ __align__(16) ushort Pb[5 * 16 * PS];
  int L = lenp[0];
  int blk = blockIdx.x;
  int hh = blk >> 8;
  int nb = blk & 255;
  int b = nb & 1;
  int n = nb >> 1;
  int s0 = n - BLK; if (s0 < 0) s0 = 0;
  int e0 = n + BLK + 1; if (e0 > L) e0 = L;
  int vn = e0 - s0;
  int tid = threadIdx.x;

  for (int i = tid; i < 32 * VTS / 2; i += 320) ((uint*)Vt)[i] = 0;
  for (int i = tid; i < 15 * QKS / 2; i += 320)
    ((uint*)(Ks + 65 * QKS))[i] = 0;
  __syncthreads();   // zero-fill and staging overlap in Vt: must be ordered
  for (int e = tid; e < 65 * 4; e += 320) {
    int r = e >> 2, c = e & 3;
    const ushort* base = qkv + ((size_t)(n * WMAX + r) * BB + b) * (3 * DD) + hh * DH;
    *(uint4*)(Ks + r * QKS + c * 8) = *(const uint4*)(base + DD + c * 8);
    uint4 vv = *(const uint4*)(base + 2 * DD + c * 8);
    const ushort* vp = (const ushort*)&vv;
#pragma unroll
    for (int u = 0; u < 8; ++u) Vt[vslot(c * 8 + u, r)] = vp[u];
  }

  int w = tid >> 6, lane = tid & 63;
  int fr = lane & 15, g = lane >> 4;
  int q0 = w * 16;
  ushort* Pw = Pb + w * 16 * PS;

  int qr_ld = q0 + fr; if (qr_ld > 64) qr_ld = 64;
  s16x8 aq = *(const s16x8*)(qkv + ((size_t)(n * WMAX + qr_ld) * BB + b) * (3 * DD)
                             + hh * DH + g * 8);
  __syncthreads();

  f32x4 sacc[5];
#pragma unroll
  for (int t = 0; t < 5; ++t) {
    s16x8 bk = *(const s16x8*)(Ks + (t * 16 + fr) * QKS + g * 8);
    f32x4 z = {0.f, 0.f, 0.f, 0.f};
    sacc[t] = __builtin_amdgcn_mfma_f32_16x16x32_bf16(aq, bk, z, 0, 0, 0);
  }
  const float scl = 0.17677669529663687f;
#pragma unroll
  for (int j = 0; j < 4; ++j) {
    float pv[5];
    float mx = -3e38f;
#pragma unroll
    for (int t = 0; t < 5; ++t) {
      bool ok = (t * 16 + fr) < vn;
      pv[t] = ok ? sacc[t][j] * scl : -3e38f;
      mx = fmaxf(mx, pv[t]);
    }
#pragma unroll
    for (int d = 1; d < 16; d <<= 1) mx = fmaxf(mx, __shfl_xor(mx, d, 64));
    float sum = 0.f;
#pragma unroll
    for (int t = 0; t < 5; ++t) {
      float e = ((t * 16 + fr) < vn) ? __expf(pv[t] - mx) : 0.f;
      pv[t] = e;
      sum += e;
    }
#pragma unroll
    for (int d = 1; d < 16; d <<= 1) sum += __shfl_xor(sum, d, 64);
    float inv = 1.f / sum;
#pragma unroll
    for (int t = 0; t < 5; ++t)
      Pw[(g * 4 + j) * PS + t * 16 + fr] = f2bf(pv[t] * inv);
  }
  {
    int zr = lane >> 2, zc = 80 + (lane & 3) * 4;
    *(uint2*)(Pw + zr * PS + zc) = make_uint2(0u, 0u);
  }
  __syncthreads();

  f32x4 oacc[2] = {};
#pragma unroll
  for (int k0 = 0; k0 < 3; ++k0) {
    s16x8 ap = *(const s16x8*)(Pw + fr * PS + k0 * 32 + g * 8);
#pragma unroll
    for (int nt = 0; nt < 2; ++nt) {
      s16x8 bv = *(const s16x8*)(Vt + vslot(nt * 16 + fr, k0 * 32 + g * 8));
      oacc[nt] = __builtin_amdgcn_mfma_f32_16x16x32_bf16(ap, bv, oacc[nt], 0, 0, 0);
    }
  }
#pragma unroll
  for (int nt = 0; nt < 2; ++nt) {
#pragma unroll
    for (int j = 0; j < 4; ++j) {
      int qr = q0 + g * 4 + j;
      if (qr < WMAX)
        o[((size_t)(n * WMAX + qr) * BB + b) * DD + hh * DH + nt * 16 + fr] =
            f2bf(oacc[nt][j]);
    }
  }
}

// ---------------------------------------------------------------------------
// Final hierarchical softmax-gather (h bf16)
// ---------------------------------------------------------------------------
__global__ __launch_bounds__(256) void k_final(
    const ushort* __restrict__ h, const float* __restrict__ kp,
    float* __restrict__ out, const int* __restrict__ lenp) {
  int L = lenp[0];
  int t = blockIdx.x >> 1, b = blockIdx.x & 1;
  float hsc = (float)L / (float)NN;
  int nlo = t - BLK; if (nlo < 0) nlo = 0;
  int nhi = t + BLK; if (nhi > NN - 1) nhi = NN - 1;
  float mx = -3e38f;
  for (int n = nlo; n <= nhi; ++n) {
    float kp0 = kp[(n * BB + b) * 2 + 0];
    float kp1 = kp[(n * BB + b) * 2 + 1];
    float dif = (float)t - (float)n * hsc - kp0;
    float lg = -dif * dif * __expf(kp1);
    mx = fmaxf(mx, lg);
  }
  float sum = 0.f, acc = 0.f;
  int c = threadIdx.x;
  for (int n = nlo; n <= nhi; ++n) {
    float kp0 = kp[(n * BB + b) * 2 + 0];
    float kp1 = kp[(n * BB + b) * 2 + 1];
    float dif = (float)t - (float)n * hsc - kp0;
    float lg = -dif * dif * __expf(kp1);
    float p = __expf(lg - mx);
    sum += p;
    int st = n - BLK; if (st < 0) st = 0;
    int w = t - st;
    acc += p * bf2f(h[(size_t)((n * WMAX + w) * BB + b) * DD + c]);
  }
  out[(size_t)(t * BB + b) * DD + c] = acc / sum;
}

// ---------------------------------------------------------------------------
extern "C" void kernel_launch(void* const* d_in, const int* in_sizes, int n_in,
                              void* d_out, int out_size, void* d_ws, size_t ws_size,
                              hipStream_t stream) {
  const float* inputs = (const float*)d_in[0];
  const float* in_W1  = (const float*)d_in[1];
  const float* in_b1  = (const float*)d_in[2];
  const float* in_W2  = (const float*)d_in[3];
  const float* in_b2  = (const float*)d_in[4];
  const float* k_W1   = (const float*)d_in[5];
  const float* k_b1   = (const float*)d_in[6];
  const float* k_W2   = (const float*)d_in[7];
  const float* k_b2   = (const float*)d_in[8];
  const float* Wqkv   = (const float*)d_in[9];
  const float* bqkv   = (const float*)d_in[10];
  const float* Wo     = (const float*)d_in[11];
  const float* bo     = (const float*)d_in[12];
  const float* ln1_g  = (const float*)d_in[13];
  const float* ln1_b  = (const float*)d_in[14];
  const float* W1     = (const float*)d_in[15];
  const float* b1     = (const float*)d_in[16];
  const float* W2     = (const float*)d_in[17];
  const float* b2     = (const float*)d_in[18];
  const float* ln2_g  = (const float*)d_in[19];
  const float* ln2_b  = (const float*)d_in[20];
  const int*   lenp   = (const int*)d_in[21];
  float* out = (float*)d_out;
  (void)in_sizes; (void)n_in; (void)ws_size;

  ushort* wsu = (ushort*)d_ws;
  size_t off = 0;
  auto alloc = [&](size_t nelem) { ushort* p = wsu + off; off += (nelem + 7) & ~7ull; return p; };
  ushort* inW1t = alloc((size_t)DFF * DIN);
  ushort* inW2t = alloc((size_t)DD * DFF);
  ushort* Wqkvt = alloc((size_t)NL * 3 * DD * DD);
  ushort* Wot   = alloc((size_t)NL * DD * DD);
  ushort* W1t   = alloc((size_t)NL * DFF * DD);
  ushort* W2t   = alloc((size_t)NL * DD * DFF);
  ushort* tq    = alloc((size_t)RROWS * DFF);   // t (R x 1024) / qkv (R x 768) share
  ushort* hb    = alloc((size_t)RROWS * DD);
  ushort* ob    = alloc((size_t)RROWS * DD);
  float*  kp    = (float*)(wsu + off);

  int L = out_size / (BB * DD);                      // 160

  TPack tp;
  tp.d[0] = {in_W1, inW1t, DIN, DFF};
  tp.d[1] = {in_W2, inW2t, DFF, DD};
  tp.d[2] = {Wqkv,                        Wqkvt,                       DD, 3 * DD};
  tp.d[3] = {Wqkv + (size_t)DD * 3 * DD,  Wqkvt + (size_t)3 * DD * DD, DD, 3 * DD};
  tp.d[4] = {Wo,                    Wot,                   DD, DD};
  tp.d[5] = {Wo + (size_t)DD * DD,  Wot + (size_t)DD * DD, DD, DD};
  tp.d[6] = {W1,                      W1t,                    DD, DFF};
  tp.d[7] = {W1 + (size_t)DD * DFF,   W1t + (size_t)DFF * DD, DD, DFF};
  tp.d[8] = {W2,                      W2t,                    DFF, DD};
  tp.d[9] = {W2 + (size_t)DFF * DD,   W2t + (size_t)DD * DFF, DFF, DD};

  k_prep<<<KP_BLOCKS + WCONV_TILES, 256, 0, stream>>>(
      tp, inputs, k_W1, k_b1, k_W2, k_b2, kp);

  // input MLP (buildx fused into inMLP1's A staging)
  k_inmlp1<<<dim3(RROWS / 128, 4), 512, 0, stream>>>(inputs, inW1t, in_b1, tq);
  k_gemm8<32, 0, 0, 128><<<dim3(RROWS / 32, 1), 512, 0, stream>>>(
      tq, inW2t, in_b2, nullptr, nullptr, nullptr, hb, DD, DFF);

  for (int l = 0; l < NL; ++l) {
    k_gemm8<128, 0, 0, 64><<<dim3(RROWS / 128, 3), 512, 0, stream>>>(
        hb, Wqkvt + (size_t)l * 3 * DD * DD, bqkv + (size_t)l * 3 * DD,
        nullptr, nullptr, nullptr, tq, 3 * DD, DD);
    k_attn<<<NN * BB * NH, 320, 0, stream>>>(tq, ob, lenp);
    k_gemm8<64, 0, 1, 128><<<dim3(RROWS / 64, 1), 512, 0, stream>>>(
        ob, Wot + (size_t)l * DD * DD, bo + (size_t)l * DD, hb,
        ln1_g + (size_t)l * DD, ln1_b + (size_t)l * DD, hb, DD, DD);
    k_gemm8<128, 1, 0, 64><<<dim3(RROWS / 128, 4), 512, 0, stream>>>(
        hb, W1t + (size_t)l * DFF * DD, b1 + (size_t)l * DFF,
        nullptr, nullptr, nullptr, tq, DFF, DD);
    k_gemm8<32, 0, 1, 128><<<dim3(RROWS / 32, 1), 512, 0, stream>>>(
        tq, W2t + (size_t)l * DD * DFF, b2 + (size_t)l * DD, hb,
        ln2_g + (size_t)l * DD, ln2_b + (size_t)l * DD, hb, DD, DFF);
  }
  k_final<<<L * BB, 256, 0, stream>>>(hb, kp, out, lenp);
}

// Round 16
// 262.267 us; speedup vs baseline: 1.0945x; 1.0945x over previous
//
#include <hip/hip_runtime.h>

constexpr int NN    = 128;
constexpr int BB    = 2;
constexpr int DIN   = 128;
constexpr int DD    = 256;
constexpr int DFF   = 1024;
constexpr int NH    = 8;
constexpr int DH    = 32;
constexpr int NL    = 2;
constexpr int BLK   = 32;
constexpr int WMAX  = 2 * BLK + 1;       // 65
constexpr int RROWS = NN * WMAX * BB;    // 16640

typedef __attribute__((ext_vector_type(8))) short s16x8;   // 8 bf16 (4 VGPR)
typedef __attribute__((ext_vector_type(4))) float f32x4;

__device__ __forceinline__ ushort f2bf(float f) {
  unsigned u = __float_as_uint(f);
  unsigned r = (u + 0x7fffu + ((u >> 16) & 1u)) >> 16;    // RNE
  return (ushort)r;
}
__device__ __forceinline__ float bf2f(ushort h) {
  return __uint_as_float(((unsigned)h) << 16);
}

// async global->LDS, 16B per lane; LDS dest must be lane-linear.
__device__ __forceinline__ void gld16(const void* g, void* l) {
  __builtin_amdgcn_global_load_lds(
      (const __attribute__((address_space(1))) void*)g,
      (__attribute__((address_space(3))) void*)l, 16, 0, 0);
}
// vmcnt(0) BEFORE any barrier that publishes global_load_lds data.
__device__ __forceinline__ void vmdrain() {
  asm volatile("s_waitcnt vmcnt(0)" ::: "memory");
}

// ---------------------------------------------------------------------------
// Fused prep: [0,256) kp rows, [256,2176) weight transpose tiles.
// ---------------------------------------------------------------------------
struct TD { const float* in; ushort* out; int K; int N; };
struct TPack { TD d[10]; };
constexpr int KP_BLOCKS   = NN * BB;             // 256
constexpr int WCONV_TILES = 1920;

__global__ __launch_bounds__(256) void k_prep(
    TPack p, const float* __restrict__ inp,
    const float* __restrict__ kW1, const float* __restrict__ kb1,
    const float* __restrict__ kW2, const float* __restrict__ kb2,
    float* __restrict__ kp) {
  __shared__ float ls[32 * 33];
  int bid = blockIdx.x;
  int tid = threadIdx.x;
  if (bid < KP_BLOCKS) {
    int row = bid;
    float* xs = ls;                 // [128]
    float* red = ls + 256;          // [8]
    if (tid < DIN) xs[tid] = inp[row * DIN + tid];
    __syncthreads();
    int j0 = tid * 4;
    float4 acc = *(const float4*)(kb1 + j0);
#pragma unroll 8
    for (int k = 0; k < DIN; ++k) {
      float xv = xs[k];
      float4 wv = *(const float4*)(kW1 + (size_t)k * DFF + j0);
      acc.x += xv * wv.x; acc.y += xv * wv.y;
      acc.z += xv * wv.z; acc.w += xv * wv.w;
    }
    acc.x = fmaxf(acc.x, 0.f); acc.y = fmaxf(acc.y, 0.f);
    acc.z = fmaxf(acc.z, 0.f); acc.w = fmaxf(acc.w, 0.f);
    float4 w2a = *(const float4*)(kW2 + 2 * j0);
    float4 w2b = *(const float4*)(kW2 + 2 * j0 + 4);
    float a0 = acc.x * w2a.x + acc.y * w2a.z + acc.z * w2b.x + acc.w * w2b.z;
    float a1 = acc.x * w2a.y + acc.y * w2a.w + acc.z * w2b.y + acc.w * w2b.w;
#pragma unroll
    for (int m = 32; m > 0; m >>= 1) {
      a0 += __shfl_xor(a0, m, 64);
      a1 += __shfl_xor(a1, m, 64);
    }
    if ((tid & 63) == 0) { red[(tid >> 6) * 2] = a0; red[(tid >> 6) * 2 + 1] = a1; }
    __syncthreads();
    if (tid == 0) {
      kp[row * 2 + 0] = red[0] + red[2] + red[4] + red[6] + kb2[0];
      kp[row * 2 + 1] = red[1] + red[3] + red[5] + red[7] + kb2[1];
    }
  } else {
    const int cum[11] = {0, 128, 384, 576, 768, 832, 896, 1152, 1408, 1664, 1920};
    int tb = bid - KP_BLOCKS;
    int mi = 0;
#pragma unroll
    for (int i = 0; i < 10; ++i) if (tb >= cum[i + 1]) mi = i + 1;
    TD t = p.d[mi];
    int tile = tb - cum[mi];
    int ntk = t.K >> 5;
    int tn = tile / ntk, tk = tile - tn * ntk;
    int r = tid >> 5, c = tid & 31;
#pragma unroll
    for (int i = 0; i < 4; ++i) {
      int kk = r + 8 * i;
      ls[kk * 33 + c] = t.in[(size_t)(tk * 32 + kk) * t.N + tn * 32 + c];
    }
    __syncthreads();
#pragma unroll
    for (int i = 0; i < 4; ++i) {
      int rr = r + 8 * i;
      t.out[(size_t)(tn * 32 + rr) * t.K + tk * 32 + c] = f2bf(ls[c * 33 + rr]);
    }
  }
}

// ---------------------------------------------------------------------------
// inMLP1: t = relu(x @ inW1^T + b1), x = inputs + PE computed on the fly.
// ---------------------------------------------------------------------------
__global__ __launch_bounds__(512) void k_inmlp1(
    const float* __restrict__ inp, const ushort* __restrict__ Bt,
    const float* __restrict__ bias, ushort* __restrict__ out) {
  __shared__ __align__(16) char As[128 * 128];   // 16 KB
  __shared__ __align__(16) char Bs[256 * 128];   // 32 KB
  int tid = threadIdx.x;
  int m0 = blockIdx.x * 128, n0 = blockIdx.y * 256;
  int lane = tid & 63, w = tid >> 6;
  int wr = w >> 2, wc = w & 3;
  int fr = lane & 15, g = lane >> 4;
  f32x4 acc[4][4] = {};

  for (int kb = 0; kb < DIN; kb += 64) {
    for (int e = tid; e < 256 * 8; e += 512) {
      int row = e >> 3, c = e & 7;
      gld16(Bt + (size_t)(n0 + row) * DIN + kb + ((c ^ (row & 7)) * 8), Bs + e * 16);
    }
    for (int e = tid; e < 128 * 8; e += 512) {
      int row = e >> 3, c = e & 7;
      int r = m0 + row;
      int n = r / (WMAX * BB);
      int rem = r - n * (WMAX * BB);
      int wn = rem >> 1, b = rem & 1;
      int st = n - BLK; if (st < 0) st = 0;
      float pos = (float)(st + wn);
      const float* ip = inp + (n * BB + b) * DIN + kb + c * 8;
      ushort vals[8];
#pragma unroll
      for (int u = 0; u < 8; ++u) {
        int i = kb + c * 8 + u;
        float div = __expf(-0.0719557841f * (float)(i & 126));
        float ang = pos * div;
        float pe = (i & 1) ? __cosf(ang) : __sinf(ang);
        vals[u] = f2bf(ip[u] + pe);
      }
      *(uint4*)(As + ((row * 128 + c * 16) ^ ((row & 7) << 4))) = *(const uint4*)vals;
    }
    vmdrain();
    __syncthreads();
#pragma unroll
    for (int ks = 0; ks < 2; ++ks) {
      int kByte = ks * 64 + g * 16;
      s16x8 a[4], b[4];
#pragma unroll
      for (int m = 0; m < 4; ++m) {
        int row = wr * 64 + m * 16 + fr;
        a[m] = *(const s16x8*)(As + ((row * 128 + kByte) ^ ((row & 7) << 4)));
      }
#pragma unroll
      for (int n = 0; n < 4; ++n) {
        int row = wc * 64 + n * 16 + fr;
        b[n] = *(const s16x8*)(Bs + ((row * 128 + kByte) ^ ((row & 7) << 4)));
      }
#pragma unroll
      for (int m = 0; m < 4; ++m)
#pragma unroll
        for (int n = 0; n < 4; ++n)
          acc[m][n] = __builtin_amdgcn_mfma_f32_16x16x32_bf16(a[m], b[n], acc[m][n], 0, 0, 0);
    }
    __syncthreads();
  }
#pragma unroll
  for (int m = 0; m < 4; ++m) {
    int rowb = m0 + wr * 64 + m * 16 + g * 4;
#pragma unroll
    for (int n = 0; n < 4; ++n) {
      int col = n0 + wc * 64 + n * 16 + fr;
      float bv = bias[col];
#pragma unroll
      for (int j = 0; j < 4; ++j)
        out[(size_t)(rowb + j) * DFF + col] = f2bf(fmaxf(acc[m][n][j] + bv, 0.f));
    }
  }
}

// ---------------------------------------------------------------------------
// 8-wave MFMA GEMM, BN=256, gld16 staging (pre-swizzled source), single
// buffer, BK template (64 or 128).
// ---------------------------------------------------------------------------
template<int BMT, int RELU, int FUSE_LN, int BK>
__global__ __launch_bounds__(512) void k_gemm8(
    const ushort* __restrict__ A, const ushort* __restrict__ Bt,
    const float* __restrict__ bias, const ushort* __restrict__ resid,
    const float* __restrict__ lng, const float* __restrict__ lnb,
    ushort* __restrict__ out, int N, int K) {
  constexpr int MF   = BMT / 32;
  constexpr int CPR  = BK / 8;
  constexpr int ROWB = BK * 2;
  __shared__ __align__(16) char As[BMT * ROWB];
  __shared__ __align__(16) char Bs[256 * ROWB];
  int tid = threadIdx.x;
  int m0 = blockIdx.x * BMT, n0 = blockIdx.y * 256;
  int lane = tid & 63, w = tid >> 6;
  int wr = w >> 2, wc = w & 3;
  int fr = lane & 15, g = lane >> 4;
  f32x4 acc[MF][4] = {};

  for (int kb = 0; kb < K; kb += BK) {
    for (int e = tid; e < BMT * CPR; e += 512) {
      int row = e / CPR, c = e % CPR;
      gld16(A + (size_t)(m0 + row) * K + kb + ((c ^ (row & 7)) * 8), As + e * 16);
    }
    for (int e = tid; e < 256 * CPR; e += 512) {
      int row = e / CPR, c = e % CPR;
      gld16(Bt + (size_t)(n0 + row) * K + kb + ((c ^ (row & 7)) * 8), Bs + e * 16);
    }
    vmdrain();
    __syncthreads();
#pragma unroll
    for (int ks = 0; ks < BK / 32; ++ks) {
      int kByte = ks * 64 + g * 16;
      s16x8 a[MF], b[4];
#pragma unroll
      for (int m = 0; m < MF; ++m) {
        int row = wr * (BMT / 2) + m * 16 + fr;
        a[m] = *(const s16x8*)(As + ((row * ROWB + kByte) ^ ((row & 7) << 4)));
      }
#pragma unroll
      for (int n = 0; n < 4; ++n) {
        int row = wc * 64 + n * 16 + fr;
        b[n] = *(const s16x8*)(Bs + ((row * ROWB + kByte) ^ ((row & 7) << 4)));
      }
#pragma unroll
      for (int m = 0; m < MF; ++m)
#pragma unroll
        for (int n = 0; n < 4; ++n)
          acc[m][n] = __builtin_amdgcn_mfma_f32_16x16x32_bf16(a[m], b[n], acc[m][n], 0, 0, 0);
    }
    __syncthreads();
  }

  if constexpr (!FUSE_LN) {
#pragma unroll
    for (int m = 0; m < MF; ++m) {
      int rowb = m0 + wr * (BMT / 2) + m * 16 + g * 4;
#pragma unroll
      for (int n = 0; n < 4; ++n) {
        int col = n0 + wc * 64 + n * 16 + fr;
        float bv = bias[col];
#pragma unroll
        for (int j = 0; j < 4; ++j) {
          float v = acc[m][n][j] + bv;
          if (RELU) v = fmaxf(v, 0.f);
          out[(size_t)(rowb + j) * N + col] = f2bf(v);
        }
      }
    }
  } else {
    float* psum = (float*)As;                 // [4][BMT]
    float* psq  = (float*)(As + 4 * BMT * 4); // [4][BMT]
#pragma unroll
    for (int m = 0; m < MF; ++m) {
      int rowb = wr * (BMT / 2) + m * 16 + g * 4;
#pragma unroll
      for (int j = 0; j < 4; ++j) {
        float ps = 0.f, pq = 0.f;
#pragma unroll
        for (int n = 0; n < 4; ++n) {
          int col = wc * 64 + n * 16 + fr;
          float v = acc[m][n][j] + bias[col]
                  + bf2f(resid[(size_t)(m0 + rowb + j) * 256 + col]);
          acc[m][n][j] = v;
          ps += v; pq += v * v;
        }
#pragma unroll
        for (int d = 1; d < 16; d <<= 1) {
          ps += __shfl_xor(ps, d, 64);
          pq += __shfl_xor(pq, d, 64);
        }
        if (fr == 0) { psum[wc * BMT + rowb + j] = ps; psq[wc * BMT + rowb + j] = pq; }
      }
    }
    __syncthreads();
#pragma unroll
    for (int m = 0; m < MF; ++m) {
      int rowb = wr * (BMT / 2) + m * 16 + g * 4;
#pragma unroll
      for (int j = 0; j < 4; ++j) {
        int lr = rowb + j;
        float sm = psum[lr] + psum[BMT + lr] + psum[2 * BMT + lr] + psum[3 * BMT + lr];
        float sq = psq[lr] + psq[BMT + lr] + psq[2 * BMT + lr] + psq[3 * BMT + lr];
        float mean = sm * (1.f / 256.f);
        float var = sq * (1.f / 256.f) - mean * mean;
        float rs = rsqrtf(var + 1e-5f);
#pragma unroll
        for (int n = 0; n < 4; ++n) {
          int col = wc * 64 + n * 16 + fr;
          float v = (acc[m][n][j] - mean) * rs * lng[col] + lnb[col];
          out[(size_t)(m0 + lr) * 256 + col] = f2bf(v);
        }
      }
    }
  }
}

// ---------------------------------------------------------------------------
// MFMA windowed attention. One block per (n,b,head), 5 waves.
// ---------------------------------------------------------------------------
constexpr int QKS = 40;
constexpr int VTS = 104;
constexpr int PS  = 104;

__device__ __forceinline__ int vslot(int d, int r) {
  int rc = r >> 3;
  int sw = (rc < 8) ? (rc ^ (d >> 3)) : rc;
  return d * VTS + sw * 8 + (r & 7);
}

__global__ __launch_bounds__(320) void k_attn(
    const ushort* __restrict__ qkv, ushort* __restrict__ o,
    const int* __restrict__ lenp) {
  __shared__ __align__(16) ushort Ks[80 * QKS];
  __shared__ __align__(16) ushort Vt[32 * VTS];
  __shared__ __align__(16) ushort Pb[5 * 16 * PS];
  int L = lenp[0];
  int blk = blockIdx.x;
  int hh = blk >> 8;
  int nb = blk & 255;
  int b = nb & 1;
  int n = nb >> 1;
  int s0 = n - BLK; if (s0 < 0) s0 = 0;
  int e0 = n + BLK + 1; if (e0 > L) e0 = L;
  int vn = e0 - s0;
  int tid = threadIdx.x;

  for (int i = tid; i < 32 * VTS / 2; i += 320) ((uint*)Vt)[i] = 0;
  for (int i = tid; i < 15 * QKS / 2; i += 320)
    ((uint*)(Ks + 65 * QKS))[i] = 0;
  __syncthreads();   // zero-fill and staging overlap in Vt: must be ordered
  for (int e = tid; e < 65 * 4; e += 320) {
    int r = e >> 2, c = e & 3;
    const ushort* base = qkv + ((size_t)(n * WMAX + r) * BB + b) * (3 * DD) + hh * DH;
    *(uint4*)(Ks + r * QKS + c * 8) = *(const uint4*)(base + DD + c * 8);
    uint4 vv = *(const uint4*)(base + 2 * DD + c * 8);
    const ushort* vp = (const ushort*)&vv;
#pragma unroll
    for (int u = 0; u < 8; ++u) Vt[vslot(c * 8 + u, r)] = vp[u];
  }

  int w = tid >> 6, lane = tid & 63;
  int fr = lane & 15, g = lane >> 4;
  int q0 = w * 16;
  ushort* Pw = Pb + w * 16 * PS;

  int qr_ld = q0 + fr; if (qr_ld > 64) qr_ld = 64;
  s16x8 aq = *(const s16x8*)(qkv + ((size_t)(n * WMAX + qr_ld) * BB + b) * (3 * DD)
                             + hh * DH + g * 8);
  __syncthreads();

  f32x4 sacc[5];
#pragma unroll
  for (int t = 0; t < 5; ++t) {
    s16x8 bk = *(const s16x8*)(Ks + (t * 16 + fr) * QKS + g * 8);
    f32x4 z = {0.f, 0.f, 0.f, 0.f};
    sacc[t] = __builtin_amdgcn_mfma_f32_16x16x32_bf16(aq, bk, z, 0, 0, 0);
  }
  const float scl = 0.17677669529663687f;
#pragma unroll
  for (int j = 0; j < 4; ++j) {
    float pv[5];
    float mx = -3e38f;
#pragma unroll
    for (int t = 0; t < 5; ++t) {
      bool ok = (t * 16 + fr) < vn;
      pv[t] = ok ? sacc[t][j] * scl : -3e38f;
      mx = fmaxf(mx, pv[t]);
    }
#pragma unroll
    for (int d = 1; d < 16; d <<= 1) mx = fmaxf(mx, __shfl_xor(mx, d, 64));
    float sum = 0.f;
#pragma unroll
    for (int t = 0; t < 5; ++t) {
      float e = ((t * 16 + fr) < vn) ? __expf(pv[t] - mx) : 0.f;
      pv[t] = e;
      sum += e;
    }
#pragma unroll
    for (int d = 1; d < 16; d <<= 1) sum += __shfl_xor(sum, d, 64);
    float inv = 1.f / sum;
#pragma unroll
    for (int t = 0; t < 5; ++t)
      Pw[(g * 4 + j) * PS + t * 16 + fr] = f2bf(pv[t] * inv);
  }
  {
    int zr = lane >> 2, zc = 80 + (lane & 3) * 4;
    *(uint2*)(Pw + zr * PS + zc) = make_uint2(0u, 0u);
  }
  __syncthreads();

  f32x4 oacc[2] = {};
#pragma unroll
  for (int k0 = 0; k0 < 3; ++k0) {
    s16x8 ap = *(const s16x8*)(Pw + fr * PS + k0 * 32 + g * 8);
#pragma unroll
    for (int nt = 0; nt < 2; ++nt) {
      s16x8 bv = *(const s16x8*)(Vt + vslot(nt * 16 + fr, k0 * 32 + g * 8));
      oacc[nt] = __builtin_amdgcn_mfma_f32_16x16x32_bf16(ap, bv, oacc[nt], 0, 0, 0);
    }
  }
#pragma unroll
  for (int nt = 0; nt < 2; ++nt) {
#pragma unroll
    for (int j = 0; j < 4; ++j) {
      int qr = q0 + g * 4 + j;
      if (qr < WMAX)
        o[((size_t)(n * WMAX + qr) * BB + b) * DD + hh * DH + nt * 16 + fr] =
            f2bf(oacc[nt][j]);
    }
  }
}

// ---------------------------------------------------------------------------
// Final hierarchical softmax-gather (h bf16)
// ---------------------------------------------------------------------------
__global__ __launch_bounds__(256) void k_final(
    const ushort* __restrict__ h, const float* __restrict__ kp,
    float* __restrict__ out, const int* __restrict__ lenp) {
  int L = lenp[0];
  int t = blockIdx.x >> 1, b = blockIdx.x & 1;
  float hsc = (float)L / (float)NN;
  int nlo = t - BLK; if (nlo < 0) nlo = 0;
  int nhi = t + BLK; if (nhi > NN - 1) nhi = NN - 1;
  float mx = -3e38f;
  for (int n = nlo; n <= nhi; ++n) {
    float kp0 = kp[(n * BB + b) * 2 + 0];
    float kp1 = kp[(n * BB + b) * 2 + 1];
    float dif = (float)t - (float)n * hsc - kp0;
    float lg = -dif * dif * __expf(kp1);
    mx = fmaxf(mx, lg);
  }
  float sum = 0.f, acc = 0.f;
  int c = threadIdx.x;
  for (int n = nlo; n <= nhi; ++n) {
    float kp0 = kp[(n * BB + b) * 2 + 0];
    float kp1 = kp[(n * BB + b) * 2 + 1];
    float dif = (float)t - (float)n * hsc - kp0;
    float lg = -dif * dif * __expf(kp1);
    float p = __expf(lg - mx);
    sum += p;
    int st = n - BLK; if (st < 0) st = 0;
    int w = t - st;
    acc += p * bf2f(h[(size_t)((n * WMAX + w) * BB + b) * DD + c]);
  }
  out[(size_t)(t * BB + b) * DD + c] = acc / sum;
}

// ---------------------------------------------------------------------------
extern "C" void kernel_launch(void* const* d_in, const int* in_sizes, int n_in,
                              void* d_out, int out_size, void* d_ws, size_t ws_size,
                              hipStream_t stream) {
  const float* inputs = (const float*)d_in[0];
  const float* in_W1  = (const float*)d_in[1];
  const float* in_b1  = (const float*)d_in[2];
  const float* in_W2  = (const float*)d_in[3];
  const float* in_b2  = (const float*)d_in[4];
  const float* k_W1   = (const float*)d_in[5];
  const float* k_b1   = (const float*)d_in[6];
  const float* k_W2   = (const float*)d_in[7];
  const float* k_b2   = (const float*)d_in[8];
  const float* Wqkv   = (const float*)d_in[9];
  const float* bqkv   = (const float*)d_in[10];
  const float* Wo     = (const float*)d_in[11];
  const float* bo     = (const float*)d_in[12];
  const float* ln1_g  = (const float*)d_in[13];
  const float* ln1_b  = (const float*)d_in[14];
  const float* W1     = (const float*)d_in[15];
  const float* b1     = (const float*)d_in[16];
  const float* W2     = (const float*)d_in[17];
  const float* b2     = (const float*)d_in[18];
  const float* ln2_g  = (const float*)d_in[19];
  const float* ln2_b  = (const float*)d_in[20];
  const int*   lenp   = (const int*)d_in[21];
  float* out = (float*)d_out;
  (void)in_sizes; (void)n_in; (void)ws_size;

  ushort* wsu = (ushort*)d_ws;
  size_t off = 0;
  auto alloc = [&](size_t nelem) { ushort* p = wsu + off; off += (nelem + 7) & ~7ull; return p; };
  ushort* inW1t = alloc((size_t)DFF * DIN);
  ushort* inW2t = alloc((size_t)DD * DFF);
  ushort* Wqkvt = alloc((size_t)NL * 3 * DD * DD);
  ushort* Wot   = alloc((size_t)NL * DD * DD);
  ushort* W1t   = alloc((size_t)NL * DFF * DD);
  ushort* W2t   = alloc((size_t)NL * DD * DFF);
  ushort* tq    = alloc((size_t)RROWS * DFF);   // t (R x 1024) / qkv (R x 768) share
  ushort* hb    = alloc((size_t)RROWS * DD);
  ushort* ob    = alloc((size_t)RROWS * DD);
  float*  kp    = (float*)(wsu + off);

  int L = out_size / (BB * DD);                      // 160

  TPack tp;
  tp.d[0] = {in_W1, inW1t, DIN, DFF};
  tp.d[1] = {in_W2, inW2t, DFF, DD};
  tp.d[2] = {Wqkv,                        Wqkvt,                       DD, 3 * DD};
  tp.d[3] = {Wqkv + (size_t)DD * 3 * DD,  Wqkvt + (size_t)3 * DD * DD, DD, 3 * DD};
  tp.d[4] = {Wo,                    Wot,                   DD, DD};
  tp.d[5] = {Wo + (size_t)DD * DD,  Wot + (size_t)DD * DD, DD, DD};
  tp.d[6] = {W1,                      W1t,                    DD, DFF};
  tp.d[7] = {W1 + (size_t)DD * DFF,   W1t + (size_t)DFF * DD, DD, DFF};
  tp.d[8] = {W2,                      W2t,                    DFF, DD};
  tp.d[9] = {W2 + (size_t)DFF * DD,   W2t + (size_t)DD * DFF, DFF, DD};

  k_prep<<<KP_BLOCKS + WCONV_TILES, 256, 0, stream>>>(
      tp, inputs, k_W1, k_b1, k_W2, k_b2, kp);

  // input MLP (buildx fused into inMLP1's A staging)
  k_inmlp1<<<dim3(RROWS / 128, 4), 512, 0, stream>>>(inputs, inW1t, in_b1, tq);
  k_gemm8<64, 0, 0, 128><<<dim3(RROWS / 64, 1), 512, 0, stream>>>(
      tq, inW2t, in_b2, nullptr, nullptr, nullptr, hb, DD, DFF);

  for (int l = 0; l < NL; ++l) {
    k_gemm8<128, 0, 0, 64><<<dim3(RROWS / 128, 3), 512, 0, stream>>>(
        hb, Wqkvt + (size_t)l * 3 * DD * DD, bqkv + (size_t)l * 3 * DD,
        nullptr, nullptr, nullptr, tq, 3 * DD, DD);
    k_attn<<<NN * BB * NH, 320, 0, stream>>>(tq, ob, lenp);
    k_gemm8<64, 0, 1, 128><<<dim3(RROWS / 64, 1), 512, 0, stream>>>(
        ob, Wot + (size_t)l * DD * DD, bo + (size_t)l * DD, hb,
        ln1_g + (size_t)l * DD, ln1_b + (size_t)l * DD, hb, DD, DD);
    k_gemm8<128, 1, 0, 64><<<dim3(RROWS / 128, 4), 512, 0, stream>>>(
        hb, W1t + (size_t)l * DFF * DD, b1 + (size_t)l * DFF,
        nullptr, nullptr, nullptr, tq, DFF, DD);
    k_gemm8<64, 0, 1, 128><<<dim3(RROWS / 64, 1), 512, 0, stream>>>(
        tq, W2t + (size_t)l * DD * DFF, b2 + (size_t)l * DD, hb,
        ln2_g + (size_t)l * DD, ln2_b + (size_t)l * DD, hb, DD, DFF);
  }
  k_final<<<L * BB, 256, 0, stream>>>(hb, kp, out, lenp);
}

// Round 17
// 261.740 us; speedup vs baseline: 1.0967x; 1.0020x over previous
//
#include <hip/hip_runtime.h>

constexpr int NN    = 128;
constexpr int BB    = 2;
constexpr int DIN   = 128;
constexpr int DD    = 256;
constexpr int DFF   = 1024;
constexpr int NH    = 8;
constexpr int DH    = 32;
constexpr int NL    = 2;
constexpr int BLK   = 32;
constexpr int WMAX  = 2 * BLK + 1;       // 65
constexpr int RROWS = NN * WMAX * BB;    // 16640

typedef __attribute__((ext_vector_type(8))) short s16x8;   // 8 bf16 (4 VGPR)
typedef __attribute__((ext_vector_type(4))) float f32x4;

__device__ __forceinline__ ushort f2bf(float f) {
  unsigned u = __float_as_uint(f);
  unsigned r = (u + 0x7fffu + ((u >> 16) & 1u)) >> 16;    // RNE
  return (ushort)r;
}
__device__ __forceinline__ float bf2f(ushort h) {
  return __uint_as_float(((unsigned)h) << 16);
}

// async global->LDS, 16B per lane; LDS dest must be lane-linear.
__device__ __forceinline__ void gld16(const void* g, void* l) {
  __builtin_amdgcn_global_load_lds(
      (const __attribute__((address_space(1))) void*)g,
      (__attribute__((address_space(3))) void*)l, 16, 0, 0);
}
// vmcnt(0) BEFORE any barrier that publishes global_load_lds data.
__device__ __forceinline__ void vmdrain() {
  asm volatile("s_waitcnt vmcnt(0)" ::: "memory");
}

// ---------------------------------------------------------------------------
// Fused prep: [0,256) kp rows, [256,2176) weight transpose tiles.
// ---------------------------------------------------------------------------
struct TD { const float* in; ushort* out; int K; int N; };
struct TPack { TD d[10]; };
constexpr int KP_BLOCKS   = NN * BB;             // 256
constexpr int WCONV_TILES = 1920;

__global__ __launch_bounds__(256) void k_prep(
    TPack p, const float* __restrict__ inp,
    const float* __restrict__ kW1, const float* __restrict__ kb1,
    const float* __restrict__ kW2, const float* __restrict__ kb2,
    float* __restrict__ kp) {
  __shared__ float ls[32 * 33];
  int bid = blockIdx.x;
  int tid = threadIdx.x;
  if (bid < KP_BLOCKS) {
    int row = bid;
    float* xs = ls;                 // [128]
    float* red = ls + 256;          // [8]
    if (tid < DIN) xs[tid] = inp[row * DIN + tid];
    __syncthreads();
    int j0 = tid * 4;
    float4 acc = *(const float4*)(kb1 + j0);
#pragma unroll 8
    for (int k = 0; k < DIN; ++k) {
      float xv = xs[k];
      float4 wv = *(const float4*)(kW1 + (size_t)k * DFF + j0);
      acc.x += xv * wv.x; acc.y += xv * wv.y;
      acc.z += xv * wv.z; acc.w += xv * wv.w;
    }
    acc.x = fmaxf(acc.x, 0.f); acc.y = fmaxf(acc.y, 0.f);
    acc.z = fmaxf(acc.z, 0.f); acc.w = fmaxf(acc.w, 0.f);
    float4 w2a = *(const float4*)(kW2 + 2 * j0);
    float4 w2b = *(const float4*)(kW2 + 2 * j0 + 4);
    float a0 = acc.x * w2a.x + acc.y * w2a.z + acc.z * w2b.x + acc.w * w2b.z;
    float a1 = acc.x * w2a.y + acc.y * w2a.w + acc.z * w2b.y + acc.w * w2b.w;
#pragma unroll
    for (int m = 32; m > 0; m >>= 1) {
      a0 += __shfl_xor(a0, m, 64);
      a1 += __shfl_xor(a1, m, 64);
    }
    if ((tid & 63) == 0) { red[(tid >> 6) * 2] = a0; red[(tid >> 6) * 2 + 1] = a1; }
    __syncthreads();
    if (tid == 0) {
      kp[row * 2 + 0] = red[0] + red[2] + red[4] + red[6] + kb2[0];
      kp[row * 2 + 1] = red[1] + red[3] + red[5] + red[7] + kb2[1];
    }
  } else {
    const int cum[11] = {0, 128, 384, 576, 768, 832, 896, 1152, 1408, 1664, 1920};
    int tb = bid - KP_BLOCKS;
    int mi = 0;
#pragma unroll
    for (int i = 0; i < 10; ++i) if (tb >= cum[i + 1]) mi = i + 1;
    TD t = p.d[mi];
    int tile = tb - cum[mi];
    int ntk = t.K >> 5;
    int tn = tile / ntk, tk = tile - tn * ntk;
    int r = tid >> 5, c = tid & 31;
#pragma unroll
    for (int i = 0; i < 4; ++i) {
      int kk = r + 8 * i;
      ls[kk * 33 + c] = t.in[(size_t)(tk * 32 + kk) * t.N + tn * 32 + c];
    }
    __syncthreads();
#pragma unroll
    for (int i = 0; i < 4; ++i) {
      int rr = r + 8 * i;
      t.out[(size_t)(tn * 32 + rr) * t.K + tk * 32 + c] = f2bf(ls[c * 33 + rr]);
    }
  }
}

// ---------------------------------------------------------------------------
// inMLP1: t = relu(x @ inW1^T + b1), x = inputs + PE computed on the fly.
// ---------------------------------------------------------------------------
__global__ __launch_bounds__(512) void k_inmlp1(
    const float* __restrict__ inp, const ushort* __restrict__ Bt,
    const float* __restrict__ bias, ushort* __restrict__ out) {
  __shared__ __align__(16) char As[128 * 128];   // 16 KB
  __shared__ __align__(16) char Bs[256 * 128];   // 32 KB
  int tid = threadIdx.x;
  int m0 = blockIdx.x * 128, n0 = blockIdx.y * 256;
  int lane = tid & 63, w = tid >> 6;
  int wr = w >> 2, wc = w & 3;
  int fr = lane & 15, g = lane >> 4;
  f32x4 acc[4][4] = {};

  for (int kb = 0; kb < DIN; kb += 64) {
    for (int e = tid; e < 256 * 8; e += 512) {
      int row = e >> 3, c = e & 7;
      gld16(Bt + (size_t)(n0 + row) * DIN + kb + ((c ^ (row & 7)) * 8), Bs + e * 16);
    }
    for (int e = tid; e < 128 * 8; e += 512) {
      int row = e >> 3, c = e & 7;
      int r = m0 + row;
      int n = r / (WMAX * BB);
      int rem = r - n * (WMAX * BB);
      int wn = rem >> 1, b = rem & 1;
      int st = n - BLK; if (st < 0) st = 0;
      float pos = (float)(st + wn);
      const float* ip = inp + (n * BB + b) * DIN + kb + c * 8;
      ushort vals[8];
#pragma unroll
      for (int u = 0; u < 8; ++u) {
        int i = kb + c * 8 + u;
        float div = __expf(-0.0719557841f * (float)(i & 126));
        float ang = pos * div;
        float pe = (i & 1) ? __cosf(ang) : __sinf(ang);
        vals[u] = f2bf(ip[u] + pe);
      }
      *(uint4*)(As + ((row * 128 + c * 16) ^ ((row & 7) << 4))) = *(const uint4*)vals;
    }
    vmdrain();
    __syncthreads();
#pragma unroll
    for (int ks = 0; ks < 2; ++ks) {
      int kByte = ks * 64 + g * 16;
      s16x8 a[4], b[4];
#pragma unroll
      for (int m = 0; m < 4; ++m) {
        int row = wr * 64 + m * 16 + fr;
        a[m] = *(const s16x8*)(As + ((row * 128 + kByte) ^ ((row & 7) << 4)));
      }
#pragma unroll
      for (int n = 0; n < 4; ++n) {
        int row = wc * 64 + n * 16 + fr;
        b[n] = *(const s16x8*)(Bs + ((row * 128 + kByte) ^ ((row & 7) << 4)));
      }
#pragma unroll
      for (int m = 0; m < 4; ++m)
#pragma unroll
        for (int n = 0; n < 4; ++n)
          acc[m][n] = __builtin_amdgcn_mfma_f32_16x16x32_bf16(a[m], b[n], acc[m][n], 0, 0, 0);
    }
    __syncthreads();
  }
#pragma unroll
  for (int m = 0; m < 4; ++m) {
    int rowb = m0 + wr * 64 + m * 16 + g * 4;
#pragma unroll
    for (int n = 0; n < 4; ++n) {
      int col = n0 + wc * 64 + n * 16 + fr;
      float bv = bias[col];
#pragma unroll
      for (int j = 0; j < 4; ++j)
        out[(size_t)(rowb + j) * DFF + col] = f2bf(fmaxf(acc[m][n][j] + bv, 0.f));
    }
  }
}

// ---------------------------------------------------------------------------
// 8-wave MFMA GEMM, BN=256, gld16 staging (pre-swizzled source), single
// buffer, BK template (64 or 128). Used for qkv / FFN1 / oproj.
// ---------------------------------------------------------------------------
template<int BMT, int RELU, int FUSE_LN, int BK>
__global__ __launch_bounds__(512) void k_gemm8(
    const ushort* __restrict__ A, const ushort* __restrict__ Bt,
    const float* __restrict__ bias, const ushort* __restrict__ resid,
    const float* __restrict__ lng, const float* __restrict__ lnb,
    ushort* __restrict__ out, int N, int K) {
  constexpr int MF   = BMT / 32;
  constexpr int CPR  = BK / 8;
  constexpr int ROWB = BK * 2;
  __shared__ __align__(16) char As[BMT * ROWB];
  __shared__ __align__(16) char Bs[256 * ROWB];
  int tid = threadIdx.x;
  int m0 = blockIdx.x * BMT, n0 = blockIdx.y * 256;
  int lane = tid & 63, w = tid >> 6;
  int wr = w >> 2, wc = w & 3;
  int fr = lane & 15, g = lane >> 4;
  f32x4 acc[MF][4] = {};

  for (int kb = 0; kb < K; kb += BK) {
    for (int e = tid; e < BMT * CPR; e += 512) {
      int row = e / CPR, c = e % CPR;
      gld16(A + (size_t)(m0 + row) * K + kb + ((c ^ (row & 7)) * 8), As + e * 16);
    }
    for (int e = tid; e < 256 * CPR; e += 512) {
      int row = e / CPR, c = e % CPR;
      gld16(Bt + (size_t)(n0 + row) * K + kb + ((c ^ (row & 7)) * 8), Bs + e * 16);
    }
    vmdrain();
    __syncthreads();
#pragma unroll
    for (int ks = 0; ks < BK / 32; ++ks) {
      int kByte = ks * 64 + g * 16;
      s16x8 a[MF], b[4];
#pragma unroll
      for (int m = 0; m < MF; ++m) {
        int row = wr * (BMT / 2) + m * 16 + fr;
        a[m] = *(const s16x8*)(As + ((row * ROWB + kByte) ^ ((row & 7) << 4)));
      }
#pragma unroll
      for (int n = 0; n < 4; ++n) {
        int row = wc * 64 + n * 16 + fr;
        b[n] = *(const s16x8*)(Bs + ((row * ROWB + kByte) ^ ((row & 7) << 4)));
      }
#pragma unroll
      for (int m = 0; m < MF; ++m)
#pragma unroll
        for (int n = 0; n < 4; ++n)
          acc[m][n] = __builtin_amdgcn_mfma_f32_16x16x32_bf16(a[m], b[n], acc[m][n], 0, 0, 0);
    }
    __syncthreads();
  }

  if constexpr (!FUSE_LN) {
#pragma unroll
    for (int m = 0; m < MF; ++m) {
      int rowb = m0 + wr * (BMT / 2) + m * 16 + g * 4;
#pragma unroll
      for (int n = 0; n < 4; ++n) {
        int col = n0 + wc * 64 + n * 16 + fr;
        float bv = bias[col];
#pragma unroll
        for (int j = 0; j < 4; ++j) {
          float v = acc[m][n][j] + bv;
          if (RELU) v = fmaxf(v, 0.f);
          out[(size_t)(rowb + j) * N + col] = f2bf(v);
        }
      }
    }
  } else {
    float* psum = (float*)As;                 // [4][BMT]
    float* psq  = (float*)(As + 4 * BMT * 4); // [4][BMT]
#pragma unroll
    for (int m = 0; m < MF; ++m) {
      int rowb = wr * (BMT / 2) + m * 16 + g * 4;
#pragma unroll
      for (int j = 0; j < 4; ++j) {
        float ps = 0.f, pq = 0.f;
#pragma unroll
        for (int n = 0; n < 4; ++n) {
          int col = wc * 64 + n * 16 + fr;
          float v = acc[m][n][j] + bias[col]
                  + bf2f(resid[(size_t)(m0 + rowb + j) * 256 + col]);
          acc[m][n][j] = v;
          ps += v; pq += v * v;
        }
#pragma unroll
        for (int d = 1; d < 16; d <<= 1) {
          ps += __shfl_xor(ps, d, 64);
          pq += __shfl_xor(pq, d, 64);
        }
        if (fr == 0) { psum[wc * BMT + rowb + j] = ps; psq[wc * BMT + rowb + j] = pq; }
      }
    }
    __syncthreads();
#pragma unroll
    for (int m = 0; m < MF; ++m) {
      int rowb = wr * (BMT / 2) + m * 16 + g * 4;
#pragma unroll
      for (int j = 0; j < 4; ++j) {
        int lr = rowb + j;
        float sm = psum[lr] + psum[BMT + lr] + psum[2 * BMT + lr] + psum[3 * BMT + lr];
        float sq = psq[lr] + psq[BMT + lr] + psq[2 * BMT + lr] + psq[3 * BMT + lr];
        float mean = sm * (1.f / 256.f);
        float var = sq * (1.f / 256.f) - mean * mean;
        float rs = rsqrtf(var + 1e-5f);
#pragma unroll
        for (int n = 0; n < 4; ++n) {
          int col = wc * 64 + n * 16 + fr;
          float v = (acc[m][n][j] - mean) * rs * lng[col] + lnb[col];
          out[(size_t)(m0 + lr) * 256 + col] = f2bf(v);
        }
      }
    }
  }
}

// ---------------------------------------------------------------------------
// Counted-vmcnt double-buffered GEMM (T3/T4 minimum pipeline) for K-heavy
// N=256 GEMMs. BMT=64, BK=64, 2 buffers = 80 KB LDS (2 blocks/CU).
// Per stage each thread issues 5 global_load_lds (A:1 + B:4). The wait is
// vmcnt(5) AFTER issuing the next stage: this wave's previous-stage loads
// are then complete; the barrier makes that true for all waves.
// ---------------------------------------------------------------------------
template<int RELU, int FUSE_LN>
__global__ __launch_bounds__(512) void k_gemmp(
    const ushort* __restrict__ A, const ushort* __restrict__ Bt,
    const float* __restrict__ bias, const ushort* __restrict__ resid,
    const float* __restrict__ lng, const float* __restrict__ lnb,
    ushort* __restrict__ out, int N, int K) {
  constexpr int BMT = 64;
  __shared__ __align__(16) char As[2 * 64 * 128];    // 16 KB
  __shared__ __align__(16) char Bs[2 * 256 * 128];   // 64 KB
  int tid = threadIdx.x;
  int m0 = blockIdx.x * BMT, n0 = blockIdx.y * 256;
  int lane = tid & 63, w = tid >> 6;
  int wr = w >> 2, wc = w & 3;
  int fr = lane & 15, g = lane >> 4;
  f32x4 acc[2][4] = {};

  auto stage = [&](int half, int tk) {
    int kb = tk * 64;
    char* Ah = As + half * (64 * 128);
    char* Bh = Bs + half * (256 * 128);
    {
      int e = tid;                  // A: 512 slots, 1/thread
      int row = e >> 3, c = e & 7;
      gld16(A + (size_t)(m0 + row) * K + kb + ((c ^ (row & 7)) * 8), Ah + e * 16);
    }
#pragma unroll
    for (int it = 0; it < 4; ++it) {  // B: 2048 slots, 4/thread
      int e = tid + it * 512;
      int row = e >> 3, c = e & 7;
      gld16(Bt + (size_t)(n0 + row) * K + kb + ((c ^ (row & 7)) * 8), Bh + e * 16);
    }
  };
  auto compute = [&](int half) {
    const char* Ah = As + half * (64 * 128);
    const char* Bh = Bs + half * (256 * 128);
#pragma unroll
    for (int ks = 0; ks < 2; ++ks) {
      int kByte = ks * 64 + g * 16;
      s16x8 a[2], b[4];
#pragma unroll
      for (int m = 0; m < 2; ++m) {
        int row = wr * 32 + m * 16 + fr;
        a[m] = *(const s16x8*)(Ah + ((row * 128 + kByte) ^ ((row & 7) << 4)));
      }
#pragma unroll
      for (int n = 0; n < 4; ++n) {
        int row = wc * 64 + n * 16 + fr;
        b[n] = *(const s16x8*)(Bh + ((row * 128 + kByte) ^ ((row & 7) << 4)));
      }
#pragma unroll
      for (int m = 0; m < 2; ++m)
#pragma unroll
        for (int n = 0; n < 4; ++n)
          acc[m][n] = __builtin_amdgcn_mfma_f32_16x16x32_bf16(a[m], b[n], acc[m][n], 0, 0, 0);
    }
  };

  int nt = K >> 6;
  stage(0, 0);
  for (int t = 0; t < nt; ++t) {
    if (t + 1 < nt) {
      stage((t + 1) & 1, t + 1);
      // wait only for the PREVIOUS stage (5 newest loads stay in flight)
      asm volatile("s_waitcnt vmcnt(5)" ::: "memory");
    } else {
      asm volatile("s_waitcnt vmcnt(0)" ::: "memory");
    }
    __syncthreads();           // all waves' stage(t) loads complete
    compute(t & 1);
    __syncthreads();           // reads done before buffer t&1 is re-staged
  }

  if constexpr (!FUSE_LN) {
#pragma unroll
    for (int m = 0; m < 2; ++m) {
      int rowb = m0 + wr * 32 + m * 16 + g * 4;
#pragma unroll
      for (int n = 0; n < 4; ++n) {
        int col = n0 + wc * 64 + n * 16 + fr;
        float bv = bias[col];
#pragma unroll
        for (int j = 0; j < 4; ++j) {
          float v = acc[m][n][j] + bv;
          if (RELU) v = fmaxf(v, 0.f);
          out[(size_t)(rowb + j) * N + col] = f2bf(v);
        }
      }
    }
  } else {
    float* psum = (float*)As;                 // [4][64]
    float* psq  = (float*)(As + 4 * 64 * 4);  // [4][64]
#pragma unroll
    for (int m = 0; m < 2; ++m) {
      int rowb = wr * 32 + m * 16 + g * 4;
#pragma unroll
      for (int j = 0; j < 4; ++j) {
        float ps = 0.f, pq = 0.f;
#pragma unroll
        for (int n = 0; n < 4; ++n) {
          int col = wc * 64 + n * 16 + fr;
          float v = acc[m][n][j] + bias[col]
                  + bf2f(resid[(size_t)(m0 + rowb + j) * 256 + col]);
          acc[m][n][j] = v;
          ps += v; pq += v * v;
        }
#pragma unroll
        for (int d = 1; d < 16; d <<= 1) {
          ps += __shfl_xor(ps, d, 64);
          pq += __shfl_xor(pq, d, 64);
        }
        if (fr == 0) { psum[wc * 64 + rowb + j] = ps; psq[wc * 64 + rowb + j] = pq; }
      }
    }
    __syncthreads();
#pragma unroll
    for (int m = 0; m < 2; ++m) {
      int rowb = wr * 32 + m * 16 + g * 4;
#pragma unroll
      for (int j = 0; j < 4; ++j) {
        int lr = rowb + j;
        float sm = psum[lr] + psum[64 + lr] + psum[128 + lr] + psum[192 + lr];
        float sq = psq[lr] + psq[64 + lr] + psq[128 + lr] + psq[192 + lr];
        float mean = sm * (1.f / 256.f);
        float var = sq * (1.f / 256.f) - mean * mean;
        float rs = rsqrtf(var + 1e-5f);
#pragma unroll
        for (int n = 0; n < 4; ++n) {
          int col = wc * 64 + n * 16 + fr;
          float v = (acc[m][n][j] - mean) * rs * lng[col] + lnb[col];
          out[(size_t)(m0 + lr) * 256 + col] = f2bf(v);
        }
      }
    }
  }
}

// ---------------------------------------------------------------------------
// MFMA windowed attention. One block per (n,b,head), 5 waves.
// ---------------------------------------------------------------------------
constexpr int QKS = 40;
constexpr int VTS = 104;
constexpr int PS  = 104;

__device__ __forceinline__ int vslot(int d, int r) {
  int rc = r >> 3;
  int sw = (rc < 8) ? (rc ^ (d >> 3)) : rc;
  return d * VTS + sw * 8 + (r & 7);
}

__global__ __launch_bounds__(320) void k_attn(
    const ushort* __restrict__ qkv, ushort* __restrict__ o,
    const int* __restrict__ lenp) {
  __shared__ __align__(16) ushort Ks[80 * QKS];
  __shared__ __align__(16) ushort Vt[32 * VTS];
  __shared__ __align__(16) ushort Pb[5 * 16 * PS];
  int L = lenp[0];
  int blk = blockIdx.x;
  int hh = blk >> 8;
  int nb = blk & 255;
  int b = nb & 1;
  int n = nb >> 1;
  int s0 = n - BLK; if (s0 < 0) s0 = 0;
  int e0 = n + BLK + 1; if (e0 > L) e0 = L;
  int vn = e0 - s0;
  int tid = threadIdx.x;

  for (int i = tid; i < 32 * VTS / 2; i += 320) ((uint*)Vt)[i] = 0;
  for (int i = tid; i < 15 * QKS / 2; i += 320)
    ((uint*)(Ks + 65 * QKS))[i] = 0;
  __syncthreads();   // zero-fill and staging overlap in Vt: must be ordered
  for (int e = tid; e < 65 * 4; e += 320) {
    int r = e >> 2, c = e & 3;
    const ushort* base = qkv + ((size_t)(n * WMAX + r) * BB + b) * (3 * DD) + hh * DH;
    *(uint4*)(Ks + r * QKS + c * 8) = *(const uint4*)(base + DD + c * 8);
    uint4 vv = *(const uint4*)(base + 2 * DD + c * 8);
    const ushort* vp = (const ushort*)&vv;
#pragma unroll
    for (int u = 0; u < 8; ++u) Vt[vslot(c * 8 + u, r)] = vp[u];
  }

  int w = tid >> 6, lane = tid & 63;
  int fr = lane & 15, g = lane >> 4;
  int q0 = w * 16;
  ushort* Pw = Pb + w * 16 * PS;

  int qr_ld = q0 + fr; if (qr_ld > 64) qr_ld = 64;
  s16x8 aq = *(const s16x8*)(qkv + ((size_t)(n * WMAX + qr_ld) * BB + b) * (3 * DD)
                             + hh * DH + g * 8);
  __syncthreads();

  f32x4 sacc[5];
#pragma unroll
  for (int t = 0; t < 5; ++t) {
    s16x8 bk = *(const s16x8*)(Ks + (t * 16 + fr) * QKS + g * 8);
    f32x4 z = {0.f, 0.f, 0.f, 0.f};
    sacc[t] = __builtin_amdgcn_mfma_f32_16x16x32_bf16(aq, bk, z, 0, 0, 0);
  }
  const float scl = 0.17677669529663687f;
#pragma unroll
  for (int j = 0; j < 4; ++j) {
    float pv[5];
    float mx = -3e38f;
#pragma unroll
    for (int t = 0; t < 5; ++t) {
      bool ok = (t * 16 + fr) < vn;
      pv[t] = ok ? sacc[t][j] * scl : -3e38f;
      mx = fmaxf(mx, pv[t]);
    }
#pragma unroll
    for (int d = 1; d < 16; d <<= 1) mx = fmaxf(mx, __shfl_xor(mx, d, 64));
    float sum = 0.f;
#pragma unroll
    for (int t = 0; t < 5; ++t) {
      float e = ((t * 16 + fr) < vn) ? __expf(pv[t] - mx) : 0.f;
      pv[t] = e;
      sum += e;
    }
#pragma unroll
    for (int d = 1; d < 16; d <<= 1) sum += __shfl_xor(sum, d, 64);
    float inv = 1.f / sum;
#pragma unroll
    for (int t = 0; t < 5; ++t)
      Pw[(g * 4 + j) * PS + t * 16 + fr] = f2bf(pv[t] * inv);
  }
  {
    int zr = lane >> 2, zc = 80 + (lane & 3) * 4;
    *(uint2*)(Pw + zr * PS + zc) = make_uint2(0u, 0u);
  }
  __syncthreads();

  f32x4 oacc[2] = {};
#pragma unroll
  for (int k0 = 0; k0 < 3; ++k0) {
    s16x8 ap = *(const s16x8*)(Pw + fr * PS + k0 * 32 + g * 8);
#pragma unroll
    for (int nt = 0; nt < 2; ++nt) {
      s16x8 bv = *(const s16x8*)(Vt + vslot(nt * 16 + fr, k0 * 32 + g * 8));
      oacc[nt] = __builtin_amdgcn_mfma_f32_16x16x32_bf16(ap, bv, oacc[nt], 0, 0, 0);
    }
  }
#pragma unroll
  for (int nt = 0; nt < 2; ++nt) {
#pragma unroll
    for (int j = 0; j < 4; ++j) {
      int qr = q0 + g * 4 + j;
      if (qr < WMAX)
        o[((size_t)(n * WMAX + qr) * BB + b) * DD + hh * DH + nt * 16 + fr] =
            f2bf(oacc[nt][j]);
    }
  }
}

// ---------------------------------------------------------------------------
// Final hierarchical softmax-gather (h bf16)
// ---------------------------------------------------------------------------
__global__ __launch_bounds__(256) void k_final(
    const ushort* __restrict__ h, const float* __restrict__ kp,
    float* __restrict__ out, const int* __restrict__ lenp) {
  int L = lenp[0];
  int t = blockIdx.x >> 1, b = blockIdx.x & 1;
  float hsc = (float)L / (float)NN;
  int nlo = t - BLK; if (nlo < 0) nlo = 0;
  int nhi = t + BLK; if (nhi > NN - 1) nhi = NN - 1;
  float mx = -3e38f;
  for (int n = nlo; n <= nhi; ++n) {
    float kp0 = kp[(n * BB + b) * 2 + 0];
    float kp1 = kp[(n * BB + b) * 2 + 1];
    float dif = (float)t - (float)n * hsc - kp0;
    float lg = -dif * dif * __expf(kp1);
    mx = fmaxf(mx, lg);
  }
  float sum = 0.f, acc = 0.f;
  int c = threadIdx.x;
  for (int n = nlo; n <= nhi; ++n) {
    float kp0 = kp[(n * BB + b) * 2 + 0];
    float kp1 = kp[(n * BB + b) * 2 + 1];
    float dif = (float)t - (float)n * hsc - kp0;
    float lg = -dif * dif * __expf(kp1);
    float p = __expf(lg - mx);
    sum += p;
    int st = n - BLK; if (st < 0) st = 0;
    int w = t - st;
    acc += p * bf2f(h[(size_t)((n * WMAX + w) * BB + b) * DD + c]);
  }
  out[(size_t)(t * BB + b) * DD + c] = acc / sum;
}

// ---------------------------------------------------------------------------
extern "C" void kernel_launch(void* const* d_in, const int* in_sizes, int n_in,
                              void* d_out, int out_size, void* d_ws, size_t ws_size,
                              hipStream_t stream) {
  const float* inputs = (const float*)d_in[0];
  const float* in_W1  = (const float*)d_in[1];
  const float* in_b1  = (const float*)d_in[2];
  const float* in_W2  = (const float*)d_in[3];
  const float* in_b2  = (const float*)d_in[4];
  const float* k_W1   = (const float*)d_in[5];
  const float* k_b1   = (const float*)d_in[6];
  const float* k_W2   = (const float*)d_in[7];
  const float* k_b2   = (const float*)d_in[8];
  const float* Wqkv   = (const float*)d_in[9];
  const float* bqkv   = (const float*)d_in[10];
  const float* Wo     = (const float*)d_in[11];
  const float* bo     = (const float*)d_in[12];
  const float* ln1_g  = (const float*)d_in[13];
  const float* ln1_b  = (const float*)d_in[14];
  const float* W1     = (const float*)d_in[15];
  const float* b1     = (const float*)d_in[16];
  const float* W2     = (const float*)d_in[17];
  const float* b2     = (const float*)d_in[18];
  const float* ln2_g  = (const float*)d_in[19];
  const float* ln2_b  = (const float*)d_in[20];
  const int*   lenp   = (const int*)d_in[21];
  float* out = (float*)d_out;
  (void)in_sizes; (void)n_in; (void)ws_size;

  ushort* wsu = (ushort*)d_ws;
  size_t off = 0;
  auto alloc = [&](size_t nelem) { ushort* p = wsu + off; off += (nelem + 7) & ~7ull; return p; };
  ushort* inW1t = alloc((size_t)DFF * DIN);
  ushort* inW2t = alloc((size_t)DD * DFF);
  ushort* Wqkvt = alloc((size_t)NL * 3 * DD * DD);
  ushort* Wot   = alloc((size_t)NL * DD * DD);
  ushort* W1t   = alloc((size_t)NL * DFF * DD);
  ushort* W2t   = alloc((size_t)NL * DD * DFF);
  ushort* tq    = alloc((size_t)RROWS * DFF);   // t (R x 1024) / qkv (R x 768) share
  ushort* hb    = alloc((size_t)RROWS * DD);
  ushort* ob    = alloc((size_t)RROWS * DD);
  float*  kp    = (float*)(wsu + off);

  int L = out_size / (BB * DD);                      // 160

  TPack tp;
  tp.d[0] = {in_W1, inW1t, DIN, DFF};
  tp.d[1] = {in_W2, inW2t, DFF, DD};
  tp.d[2] = {Wqkv,                        Wqkvt,                       DD, 3 * DD};
  tp.d[3] = {Wqkv + (size_t)DD * 3 * DD,  Wqkvt + (size_t)3 * DD * DD, DD, 3 * DD};
  tp.d[4] = {Wo,                    Wot,                   DD, DD};
  tp.d[5] = {Wo + (size_t)DD * DD,  Wot + (size_t)DD * DD, DD, DD};
  tp.d[6] = {W1,                      W1t,                    DD, DFF};
  tp.d[7] = {W1 + (size_t)DD * DFF,   W1t + (size_t)DFF * DD, DD, DFF};
  tp.d[8] = {W2,                      W2t,                    DFF, DD};
  tp.d[9] = {W2 + (size_t)DFF * DD,   W2t + (size_t)DD * DFF, DFF, DD};

  k_prep<<<KP_BLOCKS + WCONV_TILES, 256, 0, stream>>>(
      tp, inputs, k_W1, k_b1, k_W2, k_b2, kp);

  // input MLP (buildx fused into inMLP1's A staging)
  k_inmlp1<<<dim3(RROWS / 128, 4), 512, 0, stream>>>(inputs, inW1t, in_b1, tq);
  k_gemmp<0, 0><<<dim3(RROWS / 64, 1), 512, 0, stream>>>(
      tq, inW2t, in_b2, nullptr, nullptr, nullptr, hb, DD, DFF);

  for (int l = 0; l < NL; ++l) {
    k_gemm8<128, 0, 0, 64><<<dim3(RROWS / 128, 3), 512, 0, stream>>>(
        hb, Wqkvt + (size_t)l * 3 * DD * DD, bqkv + (size_t)l * 3 * DD,
        nullptr, nullptr, nullptr, tq, 3 * DD, DD);
    k_attn<<<NN * BB * NH, 320, 0, stream>>>(tq, ob, lenp);
    k_gemm8<64, 0, 1, 128><<<dim3(RROWS / 64, 1), 512, 0, stream>>>(
        ob, Wot + (size_t)l * DD * DD, bo + (size_t)l * DD, hb,
        ln1_g + (size_t)l * DD, ln1_b + (size_t)l * DD, hb, DD, DD);
    k_gemm8<128, 1, 0, 64><<<dim3(RROWS / 128, 4), 512, 0, stream>>>(
        hb, W1t + (size_t)l * DFF * DD, b1 + (size_t)l * DFF,
        nullptr, nullptr, nullptr, tq, DFF, DD);
    k_gemmp<0, 1><<<dim3(RROWS / 64, 1), 512, 0, stream>>>(
        tq, W2t + (size_t)l * DD * DFF, b2 + (size_t)l * DD, hb,
        ln2_g + (size_t)l * DD, ln2_b + (size_t)l * DD, hb, DD, DFF);
  }
  k_final<<<L * BB, 256, 0, stream>>>(hb, kp, out, lenp);
}